// Round 9
// baseline (472.663 us; speedup 1.0000x reference)
//
#include <hip/hip_runtime.h>
#include <hip/hip_bf16.h>

// MHA forward: B=1, S=4096, D=1024, H=16, HD=64, causal, fp32 I/O, bf16 MFMA compute.
// cvt(all) -> QKV gemm (swap-epilogue Q/K, pre-fragmented K/V) -> flash (32 q-rows/wave,
// kt-split x4, fixed-max exp2, XCD-local) -> Wo gemm (swap-epilogue, float4 stores).

typedef __bf16 bf16x8 __attribute__((ext_vector_type(8)));
typedef __bf16 bf16x4 __attribute__((ext_vector_type(4)));
typedef float f32x4 __attribute__((ext_vector_type(4)));
typedef short s16x4 __attribute__((ext_vector_type(4)));

#define GAS __attribute__((address_space(1)))
#define LAS __attribute__((address_space(3)))

__device__ __forceinline__ void async_copy16(const void* g, void* l) {
  __builtin_amdgcn_global_load_lds((const GAS unsigned int*)g,
                                   (LAS unsigned int*)l, 16, 0, 0);
}

__device__ __forceinline__ f32x4 mfma_k16(bf16x4 a, bf16x4 b, f32x4 c) {
  union { bf16x4 h; s16x4 s; } ua, ub;
  ua.h = a; ub.h = b;
  return __builtin_amdgcn_mfma_f32_16x16x16bf16_1k(ua.s, ub.s, c, 0, 0, 0);
}

// ---------------- fused fp32 -> bf16 convert (x, Wq|Wk|Wv, Wo) ----------------
__global__ __launch_bounds__(256) void cvt_all(const float* __restrict__ x,
                                               const float* __restrict__ Wq,
                                               const float* __restrict__ Wk,
                                               const float* __restrict__ Wv,
                                               const float* __restrict__ Wo,
                                               __bf16* __restrict__ xb,
                                               __bf16* __restrict__ Wc,
                                               __bf16* __restrict__ Wob) {
  int b = blockIdx.x;
  const float* src;
  __bf16* dst;
  if (b < 4096)      { src = x  + (b       ) * 1024; dst = xb  + (long)b * 1024; }
  else if (b < 5120) { src = Wq + (b - 4096) * 1024; dst = Wc  + (long)(b - 4096) * 1024; }
  else if (b < 6144) { src = Wk + (b - 5120) * 1024; dst = Wc  + (1l << 20) + (long)(b - 5120) * 1024; }
  else if (b < 7168) { src = Wv + (b - 6144) * 1024; dst = Wc  + (2l << 20) + (long)(b - 6144) * 1024; }
  else               { src = Wo + (b - 7168) * 1024; dst = Wob + (long)(b - 7168) * 1024; }
  int i = threadIdx.x * 4;
  float4 f = *(const float4*)(src + i);
  bf16x4 o;
  o[0] = (__bf16)f.x; o[1] = (__bf16)f.y; o[2] = (__bf16)f.z; o[3] = (__bf16)f.w;
  *(bf16x4*)(dst + i) = o;
}

// ---------------- QKV GEMM: [4096,3072] = x[4096,1024] @ Wc[3072,1024]^T ----------------
// Q,K blocks use swapped MFMA (threads hold 4 consecutive out-cols -> vector stores).
// cols    0..1023 -> Qb row-major (scaled by 0.125*log2e), uint2 stores
// cols 1024..2047 -> Kf fragment layout, uint2 stores
// cols 2048..3071 -> Vf fragment layout (non-swapped), uint2 stores
// Frag layouts (per (h, 64-kt tile), 8 frags x 512 elems, flash loads frag_base + lane*8):
//   Kf frag(j,kk), lane(quad,l15): K[kt = j*16+l15][d = kk*32+quad*8+e], e=0..7
//   Vf frag(jd,jp), lane(quad,l15): V^T[d = jd*16+l15][kt = jp*32+(e>>2)*16+quad*4+(e&3)]
__global__ __launch_bounds__(256) void gemm_qkv(const __bf16* __restrict__ A,
                                                const __bf16* __restrict__ B,
                                                __bf16* __restrict__ Qb,
                                                __bf16* __restrict__ Kf,
                                                __bf16* __restrict__ Vf) {
  const int K = 1024;
  __shared__ __bf16 As[128 * 32];
  __shared__ __bf16 Bs[128 * 32];
  const int tid = threadIdx.x;
  const int lane = tid & 63, wv = tid >> 6;
  const int l15 = lane & 15, quad = lane >> 4;
  const int wm = wv >> 1, wn = wv & 1;
  const int mbase = blockIdx.y * 128, nbase = blockIdx.x * 128;
  const bool swp = (nbase < 2048);  // block-uniform: Q and K swapped, V not

  f32x4 acc[4][4] = {};

  for (int k0 = 0; k0 < K; k0 += 32) {
    __syncthreads();
#pragma unroll
    for (int q = 0; q < 2; ++q) {
      int i = q * 256 + tid;
      int row = i >> 2, kg = i & 3;
      const __bf16* ga = A + (long)(mbase + row) * K + k0 + kg * 8;
      const __bf16* gb = B + (long)(nbase + row) * K + k0 + kg * 8;
      char* la = (char*)As + (q * 256 + wv * 64) * 16;
      char* lb = (char*)Bs + (q * 256 + wv * 64) * 16;
      async_copy16(ga, la);
      async_copy16(gb, lb);
    }
    __syncthreads();
    bf16x8 af[4], bfr[4];
#pragma unroll
    for (int i = 0; i < 4; ++i)
      af[i] = *(const bf16x8*)&As[(wm * 64 + i * 16 + l15) * 32 + quad * 8];
#pragma unroll
    for (int j = 0; j < 4; ++j)
      bfr[j] = *(const bf16x8*)&Bs[(wn * 64 + j * 16 + l15) * 32 + quad * 8];
    if (swp) {
#pragma unroll
      for (int i = 0; i < 4; ++i)
#pragma unroll
        for (int j = 0; j < 4; ++j)
          acc[i][j] = __builtin_amdgcn_mfma_f32_16x16x32_bf16(bfr[j], af[i], acc[i][j], 0, 0, 0);
    } else {
#pragma unroll
      for (int i = 0; i < 4; ++i)
#pragma unroll
        for (int j = 0; j < 4; ++j)
          acc[i][j] = __builtin_amdgcn_mfma_f32_16x16x32_bf16(af[i], bfr[j], acc[i][j], 0, 0, 0);
    }
  }

  if (nbase < 1024) {
    // Q (swapped): thread holds row = mbase+wm*64+i*16+l15, cols cb..cb+3
    const float QS = 0.18033688011112043f;  // 0.125 * log2(e)
#pragma unroll
    for (int i = 0; i < 4; ++i) {
      int row = mbase + wm * 64 + i * 16 + l15;
#pragma unroll
      for (int j = 0; j < 4; ++j) {
        int cb = nbase + wn * 64 + j * 16 + quad * 4;
        union { __bf16 b[4]; uint2 u; } pk;
#pragma unroll
        for (int r = 0; r < 4; ++r) pk.b[r] = (__bf16)(acc[i][j][r] * QS);
        *(uint2*)(Qb + (long)row * 1024 + cb) = pk.u;
      }
    }
  } else if (nbase < 2048) {
    // K (swapped): acc[i][j][r] = K^T[d = nbase-1024+wn*64+j*16+quad*4+r][kt = mbase+wm*64+i*16+l15]
#pragma unroll
    for (int i = 0; i < 4; ++i)
#pragma unroll
      for (int j = 0; j < 4; ++j) {
        int d0 = nbase - 1024 + wn * 64 + j * 16 + quad * 4;  // 4 consecutive d
        int h = d0 >> 6, dd = d0 & 63;
        int kk = dd >> 5, qf = (dd >> 3) & 3, e0 = dd & 7;    // e0 in {0,4}
        int kt = mbase + wm * 64 + i * 16 + l15;
        int tile = kt >> 6;
        long off = ((long)(h * 64 + tile) * 8 + i * 2 + kk) * 512 + (qf * 16 + l15) * 8 + e0;
        union { __bf16 b[4]; uint2 u; } pk;
#pragma unroll
        for (int r = 0; r < 4; ++r) pk.b[r] = (__bf16)acc[i][j][r];
        *(uint2*)(Kf + off) = pk.u;
      }
  } else {
    // V (non-swapped): acc[i][j][r] = V[kt = mbase+wm*64+i*16+quad*4+r][d = nbase-2048+wn*64+j*16+l15]
#pragma unroll
    for (int i = 0; i < 4; ++i)
#pragma unroll
      for (int j = 0; j < 4; ++j) {
        int col = nbase - 2048 + wn * 64 + j * 16 + l15;
        int h = col >> 6, dd = col & 63;
        int jd = dd >> 4, lv = dd & 15;
        int kt0 = mbase + wm * 64 + i * 16 + quad * 4;   // 4 consecutive kt
        int tile = kt0 >> 6, w6 = kt0 & 63;
        int jp = w6 >> 5, bit4 = (w6 >> 4) & 1, qv = (w6 >> 2) & 3;
        long off = ((long)(h * 64 + tile) * 8 + jd * 2 + jp) * 512 + (qv * 16 + lv) * 8 + bit4 * 4;
        union { __bf16 b[4]; uint2 u; } pk;
#pragma unroll
        for (int r = 0; r < 4; ++r) pk.b[r] = (__bf16)acc[i][j][r];
        *(uint2*)(Vf + off) = pk.u;
      }
  }
}

// ---------------- Wo GEMM: out[4096,1024] = AO[4096,1024] @ Wo[1024,1024]^T (fp32 out) ----------------
// 128x64 tiles, swapped MFMA -> float4 epilogue stores. 512 blocks (2/CU).
__global__ __launch_bounds__(256) void gemm_wo(const __bf16* __restrict__ A,
                                               const __bf16* __restrict__ B,
                                               float* __restrict__ C) {
  const int K = 1024, N = 1024;
  __shared__ __bf16 As[128 * 32];
  __shared__ __bf16 Bs[64 * 32];
  const int tid = threadIdx.x;
  const int lane = tid & 63, wv = tid >> 6;
  const int l15 = lane & 15, quad = lane >> 4;
  const int wm = wv >> 1, wn = wv & 1;
  const int mbase = blockIdx.y * 128, nbase = blockIdx.x * 64;

  f32x4 acc[4][2] = {};

  for (int k0 = 0; k0 < K; k0 += 32) {
    __syncthreads();
#pragma unroll
    for (int q = 0; q < 2; ++q) {
      int i = q * 256 + tid;
      int row = i >> 2, kg = i & 3;
      const __bf16* ga = A + (long)(mbase + row) * K + k0 + kg * 8;
      char* la = (char*)As + (q * 256 + wv * 64) * 16;
      async_copy16(ga, la);
    }
    {
      int row = tid >> 2, kg = tid & 3;
      const __bf16* gb = B + (long)(nbase + row) * K + k0 + kg * 8;
      char* lb = (char*)Bs + (wv * 64) * 16;
      async_copy16(gb, lb);
    }
    __syncthreads();
    bf16x8 af[4], bfr[2];
#pragma unroll
    for (int i = 0; i < 4; ++i)
      af[i] = *(const bf16x8*)&As[(wm * 64 + i * 16 + l15) * 32 + quad * 8];
#pragma unroll
    for (int j = 0; j < 2; ++j)
      bfr[j] = *(const bf16x8*)&Bs[(wn * 32 + j * 16 + l15) * 32 + quad * 8];
#pragma unroll
    for (int i = 0; i < 4; ++i)
#pragma unroll
      for (int j = 0; j < 2; ++j)
        acc[i][j] = __builtin_amdgcn_mfma_f32_16x16x32_bf16(bfr[j], af[i], acc[i][j], 0, 0, 0);
  }
  // swapped epilogue: row = ...+l15, cols = ...+quad*4+{0..3} -> float4 stores
#pragma unroll
  for (int i = 0; i < 4; ++i) {
    int row = mbase + wm * 64 + i * 16 + l15;
#pragma unroll
    for (int j = 0; j < 2; ++j) {
      int cb = nbase + wn * 32 + j * 16 + quad * 4;
      *(f32x4*)(C + (long)row * N + cb) = acc[i][j];
    }
  }
}

// ---------------- Flash attention (32 q-rows/wave, kt-split x4, XCD-local) ----------------
// Fixed-max softmax => l/o are plain sums over kt => kt-range splittable.
// Grid 512 x 512 thr (8 waves = 2 pairs x 4 quarters). Block b: h = (b&7)+8*((b>>3)&1),
// rest = b>>4 (0..31). Wave w: pr = w>>2, qtr = w&3. P = rest*2+pr (0..63).
// Passes: T = P then 127-P (32 q-rows); nkt = (T>>1)+1; quarter does [nkt*qtr/4, nkt*(qtr+1)/4).
// 4096 waves = 4 waves/SIMD (R8 was grid-limited at 2). 3-writer LDS merge per pair.
__global__ __launch_bounds__(512, 4) void flash_attn(const __bf16* __restrict__ Qb,
                                                     const __bf16* __restrict__ Kf,
                                                     const __bf16* __restrict__ Vf,
                                                     __bf16* __restrict__ AO) {
  __shared__ float Ms[2][3][64][34];            // [pair][writer qtr-1][lane][32 o + 2 l]
  const int tid = threadIdx.x;
  const int lane = tid & 63, l15 = lane & 15, quad = lane >> 4;
  const int w = tid >> 6;                       // 0..7
  const int pr = w >> 2, qtr = w & 3;
  const int b = blockIdx.x;
  const int h = (b & 7) + 8 * ((b >> 3) & 1);
  const int rest = b >> 4;                      // 0..31
  const int P = rest * 2 + pr;                  // 0..63
  const int hoff = h * 64;

  const __bf16* Kh = Kf + (long)h * 64 * 4096;  // 64 tiles x 4096 elems
  const __bf16* Vh = Vf + (long)h * 64 * 4096;

  for (int pass = 0; pass < 2; ++pass) {
    const int T = pass ? (127 - P) : P;         // 32-row super-tile 0..127
    bf16x8 qf[2][2];
#pragma unroll
    for (int g = 0; g < 2; ++g) {
      const int qrow = T * 32 + g * 16 + l15;
      qf[g][0] = *(const bf16x8*)(Qb + (long)qrow * 1024 + hoff + quad * 8);
      qf[g][1] = *(const bf16x8*)(Qb + (long)qrow * 1024 + hoff + 32 + quad * 8);
    }

    const int nkt = (T >> 1) + 1;
    const int kt0 = (nkt * qtr) >> 2;
    const int kt1 = (nkt * (qtr + 1)) >> 2;
    f32x4 o_acc[2][4] = {};
    float l_acc[2] = {0.0f, 0.0f};

    // prefetch K frags for first kt (coalesced: lane*16B contiguous)
    bf16x8 kc[8];
    if (kt0 < kt1) {
      const __bf16* Kt = Kh + (long)kt0 * 4096;
#pragma unroll
      for (int f = 0; f < 8; ++f)
        kc[f] = *(const bf16x8*)(Kt + f * 512 + lane * 8);
    }

    for (int kt = kt0; kt < kt1; ++kt) {
      const __bf16* Vt = Vh + (long)kt * 4096;

      // V frags for this kt (issued early; used at the end of the iter)
      bf16x8 va[8];
#pragma unroll
      for (int f = 0; f < 8; ++f)
        va[f] = *(const bf16x8*)(Vt + f * 512 + lane * 8);

      // S^T: st[g][j][r] = S[q = T*32+g*16+l15][kt*64 + j*16 + quad*4 + r]
      f32x4 st[2][4] = {};
#pragma unroll
      for (int g = 0; g < 2; ++g)
#pragma unroll
        for (int j = 0; j < 4; ++j) {
          st[g][j] = __builtin_amdgcn_mfma_f32_16x16x32_bf16(kc[j * 2 + 0], qf[g][0], st[g][j], 0, 0, 0);
          st[g][j] = __builtin_amdgcn_mfma_f32_16x16x32_bf16(kc[j * 2 + 1], qf[g][1], st[g][j], 0, 0, 0);
        }

      // prefetch next K tile while softmax+PV run
      if (kt + 1 < kt1) {
        const __bf16* Kt = Kh + (long)(kt + 1) * 4096;
#pragma unroll
        for (int f = 0; f < 8; ++f)
          kc[f] = *(const bf16x8*)(Kt + f * 512 + lane * 8);
      }

      // causal mask (only the global last tile is partial; always in quarter 3)
      if (kt == nkt - 1) {
#pragma unroll
        for (int g = 0; g < 2; ++g) {
          const int dq = (T & 1) * 32 + g * 16 + l15;   // qrow - kt*64
#pragma unroll
          for (int j = 0; j < 4; ++j)
#pragma unroll
            for (int r = 0; r < 4; ++r)
              if (j * 16 + quad * 4 + r > dq) st[g][j][r] = -3.0e38f;
        }
      }

      // fixed-max softmax: p = 2^s (exact by shift-invariance; |s| bounded)
      bf16x4 pb[2][4];
#pragma unroll
      for (int g = 0; g < 2; ++g) {
        float ps = 0.0f;
#pragma unroll
        for (int j = 0; j < 4; ++j) {
          f32x4 pj;
#pragma unroll
          for (int r = 0; r < 4; ++r) pj[r] = __builtin_amdgcn_exp2f(st[g][j][r]);
          ps += (pj[0] + pj[1]) + (pj[2] + pj[3]);
          bf16x4 bb;
#pragma unroll
          for (int r = 0; r < 4; ++r) bb[r] = (__bf16)pj[r];
          pb[g][j] = bb;
        }
        l_acc[g] += ps;
      }

      // O^T += V^T * P^T : P^T already in K16 B-frag layout (registers)
#pragma unroll
      for (int g = 0; g < 2; ++g)
#pragma unroll
        for (int j = 0; j < 4; ++j) {
          bf16x4 pbj = pb[g][j];
#pragma unroll
          for (int jd = 0; jd < 4; ++jd) {
            bf16x8 v8 = va[jd * 2 + (j >> 1)];
            bf16x4 a4 = (j & 1) ? __builtin_shufflevector(v8, v8, 4, 5, 6, 7)
                                : __builtin_shufflevector(v8, v8, 0, 1, 2, 3);
            o_acc[g][jd] = mfma_k16(a4, pbj, o_acc[g][jd]);
          }
        }
    }

    // ---- merge 4 quarters via LDS (fixed-max => plain sums) ----
    if (qtr) {
#pragma unroll
      for (int g = 0; g < 2; ++g) {
#pragma unroll
        for (int jd = 0; jd < 4; ++jd)
#pragma unroll
          for (int r = 0; r < 4; ++r)
            Ms[pr][qtr - 1][lane][g * 16 + jd * 4 + r] = o_acc[g][jd][r];
        Ms[pr][qtr - 1][lane][32 + g] = l_acc[g];
      }
    }
    __syncthreads();
    if (!qtr) {
#pragma unroll
      for (int g = 0; g < 2; ++g) {
#pragma unroll
        for (int s = 0; s < 3; ++s)
#pragma unroll
          for (int jd = 0; jd < 4; ++jd)
#pragma unroll
            for (int r = 0; r < 4; ++r)
              o_acc[g][jd][r] += Ms[pr][s][lane][g * 16 + jd * 4 + r];
        float la = l_acc[g] + Ms[pr][0][lane][32 + g] + Ms[pr][1][lane][32 + g] + Ms[pr][2][lane][32 + g];
        la += __shfl_xor(la, 16);
        la += __shfl_xor(la, 32);
        const float inv = 1.0f / la;
        const int qrow = T * 32 + g * 16 + l15;
#pragma unroll
        for (int jd = 0; jd < 4; ++jd) {
          bf16x4 ob;
#pragma unroll
          for (int r = 0; r < 4; ++r) ob[r] = (__bf16)(o_acc[g][jd][r] * inv);
          *(bf16x4*)(AO + (long)qrow * 1024 + hoff + jd * 16 + quad * 4) = ob;
        }
      }
    }
    __syncthreads();  // Ms reused next pass
  }
}

// ---------------- launch ----------------
extern "C" void kernel_launch(void* const* d_in, const int* in_sizes, int n_in,
                              void* d_out, int out_size, void* d_ws, size_t ws_size,
                              hipStream_t stream) {
  const float* x  = (const float*)d_in[0];
  // d_in[1] = causal mask (structure known -> unused)
  const float* Wq = (const float*)d_in[2];
  const float* Wk = (const float*)d_in[3];
  const float* Wv = (const float*)d_in[4];
  const float* Wo = (const float*)d_in[5];
  float* out = (float*)d_out;

  char* ws = (char*)d_ws;
  __bf16* xb  = (__bf16*)ws;                    // 8 MB  [4096,1024]
  __bf16* Wc  = (__bf16*)(ws + (8u << 20));     // 6 MB  [3072,1024] = [Wq;Wk;Wv]
  __bf16* Wob = (__bf16*)(ws + (14u << 20));    // 2 MB  [1024,1024]
  __bf16* Qb  = (__bf16*)(ws + (16u << 20));    // 8 MB  [4096,1024]
  __bf16* Kfr = (__bf16*)(ws + (24u << 20));    // 8 MB  fragmented K
  __bf16* Vfr = (__bf16*)(ws + (32u << 20));    // 8 MB  fragmented V^T
  __bf16* AO  = (__bf16*)(ws + (40u << 20));    // 8 MB  [4096,1024]

  cvt_all<<<8192, 256, 0, stream>>>(x, Wq, Wk, Wv, Wo, xb, Wc, Wob);

  dim3 g1(3072 / 128, 4096 / 128);
  gemm_qkv<<<g1, 256, 0, stream>>>(xb, Wc, Qb, Kfr, Vfr);

  flash_attn<<<512, 512, 0, stream>>>(Qb, Kfr, Vfr, AO);

  dim3 g2(1024 / 64, 4096 / 128);
  gemm_wo<<<g2, 256, 0, stream>>>(AO, Wob, out);
}

// Round 10
// 241.274 us; speedup vs baseline: 1.9590x; 1.9590x over previous
//
#include <hip/hip_runtime.h>
#include <hip/hip_bf16.h>

// MHA forward: B=1, S=4096, D=1024, H=16, HD=64, causal, fp32 I/O, bf16 MFMA compute.
// cvt(all) -> QKV gemm (swap-epilogue Q/K, pre-fragmented K/V) -> flash (32 q-rows/wave,
// kt-split x4, fixed-max exp2, XCD-local) -> Wo gemm (swap-epilogue, float4 stores).
// R10: flash launch_bounds (512,2) — R9's (512,4) halved the VGPR budget and caused
// 1.3 GB of scratch spill; occupancy comes from the 512-block grid, not the allocator.

typedef __bf16 bf16x8 __attribute__((ext_vector_type(8)));
typedef __bf16 bf16x4 __attribute__((ext_vector_type(4)));
typedef float f32x4 __attribute__((ext_vector_type(4)));
typedef short s16x4 __attribute__((ext_vector_type(4)));

#define GAS __attribute__((address_space(1)))
#define LAS __attribute__((address_space(3)))

__device__ __forceinline__ void async_copy16(const void* g, void* l) {
  __builtin_amdgcn_global_load_lds((const GAS unsigned int*)g,
                                   (LAS unsigned int*)l, 16, 0, 0);
}

__device__ __forceinline__ f32x4 mfma_k16(bf16x4 a, bf16x4 b, f32x4 c) {
  union { bf16x4 h; s16x4 s; } ua, ub;
  ua.h = a; ub.h = b;
  return __builtin_amdgcn_mfma_f32_16x16x16bf16_1k(ua.s, ub.s, c, 0, 0, 0);
}

// ---------------- fused fp32 -> bf16 convert (x, Wq|Wk|Wv, Wo) ----------------
__global__ __launch_bounds__(256) void cvt_all(const float* __restrict__ x,
                                               const float* __restrict__ Wq,
                                               const float* __restrict__ Wk,
                                               const float* __restrict__ Wv,
                                               const float* __restrict__ Wo,
                                               __bf16* __restrict__ xb,
                                               __bf16* __restrict__ Wc,
                                               __bf16* __restrict__ Wob) {
  int b = blockIdx.x;
  const float* src;
  __bf16* dst;
  if (b < 4096)      { src = x  + (b       ) * 1024; dst = xb  + (long)b * 1024; }
  else if (b < 5120) { src = Wq + (b - 4096) * 1024; dst = Wc  + (long)(b - 4096) * 1024; }
  else if (b < 6144) { src = Wk + (b - 5120) * 1024; dst = Wc  + (1l << 20) + (long)(b - 5120) * 1024; }
  else if (b < 7168) { src = Wv + (b - 6144) * 1024; dst = Wc  + (2l << 20) + (long)(b - 6144) * 1024; }
  else               { src = Wo + (b - 7168) * 1024; dst = Wob + (long)(b - 7168) * 1024; }
  int i = threadIdx.x * 4;
  float4 f = *(const float4*)(src + i);
  bf16x4 o;
  o[0] = (__bf16)f.x; o[1] = (__bf16)f.y; o[2] = (__bf16)f.z; o[3] = (__bf16)f.w;
  *(bf16x4*)(dst + i) = o;
}

// ---------------- QKV GEMM: [4096,3072] = x[4096,1024] @ Wc[3072,1024]^T ----------------
// Q,K blocks use swapped MFMA (threads hold 4 consecutive out-cols -> vector stores).
// cols    0..1023 -> Qb row-major (scaled by 0.125*log2e), uint2 stores
// cols 1024..2047 -> Kf fragment layout, uint2 stores
// cols 2048..3071 -> Vf fragment layout (non-swapped), uint2 stores
// Frag layouts (per (h, 64-kt tile), 8 frags x 512 elems, flash loads frag_base + lane*8):
//   Kf frag(j,kk), lane(quad,l15): K[kt = j*16+l15][d = kk*32+quad*8+e], e=0..7
//   Vf frag(jd,jp), lane(quad,l15): V^T[d = jd*16+l15][kt = jp*32+(e>>2)*16+quad*4+(e&3)]
__global__ __launch_bounds__(256) void gemm_qkv(const __bf16* __restrict__ A,
                                                const __bf16* __restrict__ B,
                                                __bf16* __restrict__ Qb,
                                                __bf16* __restrict__ Kf,
                                                __bf16* __restrict__ Vf) {
  const int K = 1024;
  __shared__ __bf16 As[128 * 32];
  __shared__ __bf16 Bs[128 * 32];
  const int tid = threadIdx.x;
  const int lane = tid & 63, wv = tid >> 6;
  const int l15 = lane & 15, quad = lane >> 4;
  const int wm = wv >> 1, wn = wv & 1;
  const int mbase = blockIdx.y * 128, nbase = blockIdx.x * 128;
  const bool swp = (nbase < 2048);  // block-uniform: Q and K swapped, V not

  f32x4 acc[4][4] = {};

  for (int k0 = 0; k0 < K; k0 += 32) {
    __syncthreads();
#pragma unroll
    for (int q = 0; q < 2; ++q) {
      int i = q * 256 + tid;
      int row = i >> 2, kg = i & 3;
      const __bf16* ga = A + (long)(mbase + row) * K + k0 + kg * 8;
      const __bf16* gb = B + (long)(nbase + row) * K + k0 + kg * 8;
      char* la = (char*)As + (q * 256 + wv * 64) * 16;
      char* lb = (char*)Bs + (q * 256 + wv * 64) * 16;
      async_copy16(ga, la);
      async_copy16(gb, lb);
    }
    __syncthreads();
    bf16x8 af[4], bfr[4];
#pragma unroll
    for (int i = 0; i < 4; ++i)
      af[i] = *(const bf16x8*)&As[(wm * 64 + i * 16 + l15) * 32 + quad * 8];
#pragma unroll
    for (int j = 0; j < 4; ++j)
      bfr[j] = *(const bf16x8*)&Bs[(wn * 64 + j * 16 + l15) * 32 + quad * 8];
    if (swp) {
#pragma unroll
      for (int i = 0; i < 4; ++i)
#pragma unroll
        for (int j = 0; j < 4; ++j)
          acc[i][j] = __builtin_amdgcn_mfma_f32_16x16x32_bf16(bfr[j], af[i], acc[i][j], 0, 0, 0);
    } else {
#pragma unroll
      for (int i = 0; i < 4; ++i)
#pragma unroll
        for (int j = 0; j < 4; ++j)
          acc[i][j] = __builtin_amdgcn_mfma_f32_16x16x32_bf16(af[i], bfr[j], acc[i][j], 0, 0, 0);
    }
  }

  if (nbase < 1024) {
    // Q (swapped): thread holds row = mbase+wm*64+i*16+l15, cols cb..cb+3
    const float QS = 0.18033688011112043f;  // 0.125 * log2(e)
#pragma unroll
    for (int i = 0; i < 4; ++i) {
      int row = mbase + wm * 64 + i * 16 + l15;
#pragma unroll
      for (int j = 0; j < 4; ++j) {
        int cb = nbase + wn * 64 + j * 16 + quad * 4;
        union { __bf16 b[4]; uint2 u; } pk;
#pragma unroll
        for (int r = 0; r < 4; ++r) pk.b[r] = (__bf16)(acc[i][j][r] * QS);
        *(uint2*)(Qb + (long)row * 1024 + cb) = pk.u;
      }
    }
  } else if (nbase < 2048) {
    // K (swapped): acc[i][j][r] = K^T[d = nbase-1024+wn*64+j*16+quad*4+r][kt = mbase+wm*64+i*16+l15]
#pragma unroll
    for (int i = 0; i < 4; ++i)
#pragma unroll
      for (int j = 0; j < 4; ++j) {
        int d0 = nbase - 1024 + wn * 64 + j * 16 + quad * 4;  // 4 consecutive d
        int h = d0 >> 6, dd = d0 & 63;
        int kk = dd >> 5, qf = (dd >> 3) & 3, e0 = dd & 7;    // e0 in {0,4}
        int kt = mbase + wm * 64 + i * 16 + l15;
        int tile = kt >> 6;
        long off = ((long)(h * 64 + tile) * 8 + i * 2 + kk) * 512 + (qf * 16 + l15) * 8 + e0;
        union { __bf16 b[4]; uint2 u; } pk;
#pragma unroll
        for (int r = 0; r < 4; ++r) pk.b[r] = (__bf16)acc[i][j][r];
        *(uint2*)(Kf + off) = pk.u;
      }
  } else {
    // V (non-swapped): acc[i][j][r] = V[kt = mbase+wm*64+i*16+quad*4+r][d = nbase-2048+wn*64+j*16+l15]
#pragma unroll
    for (int i = 0; i < 4; ++i)
#pragma unroll
      for (int j = 0; j < 4; ++j) {
        int col = nbase - 2048 + wn * 64 + j * 16 + l15;
        int h = col >> 6, dd = col & 63;
        int jd = dd >> 4, lv = dd & 15;
        int kt0 = mbase + wm * 64 + i * 16 + quad * 4;   // 4 consecutive kt
        int tile = kt0 >> 6, w6 = kt0 & 63;
        int jp = w6 >> 5, bit4 = (w6 >> 4) & 1, qv = (w6 >> 2) & 3;
        long off = ((long)(h * 64 + tile) * 8 + jd * 2 + jp) * 512 + (qv * 16 + lv) * 8 + bit4 * 4;
        union { __bf16 b[4]; uint2 u; } pk;
#pragma unroll
        for (int r = 0; r < 4; ++r) pk.b[r] = (__bf16)acc[i][j][r];
        *(uint2*)(Vf + off) = pk.u;
      }
  }
}

// ---------------- Wo GEMM: out[4096,1024] = AO[4096,1024] @ Wo[1024,1024]^T (fp32 out) ----------------
// 128x64 tiles, swapped MFMA -> float4 epilogue stores. 512 blocks (2/CU).
__global__ __launch_bounds__(256) void gemm_wo(const __bf16* __restrict__ A,
                                               const __bf16* __restrict__ B,
                                               float* __restrict__ C) {
  const int K = 1024, N = 1024;
  __shared__ __bf16 As[128 * 32];
  __shared__ __bf16 Bs[64 * 32];
  const int tid = threadIdx.x;
  const int lane = tid & 63, wv = tid >> 6;
  const int l15 = lane & 15, quad = lane >> 4;
  const int wm = wv >> 1, wn = wv & 1;
  const int mbase = blockIdx.y * 128, nbase = blockIdx.x * 64;

  f32x4 acc[4][2] = {};

  for (int k0 = 0; k0 < K; k0 += 32) {
    __syncthreads();
#pragma unroll
    for (int q = 0; q < 2; ++q) {
      int i = q * 256 + tid;
      int row = i >> 2, kg = i & 3;
      const __bf16* ga = A + (long)(mbase + row) * K + k0 + kg * 8;
      char* la = (char*)As + (q * 256 + wv * 64) * 16;
      async_copy16(ga, la);
    }
    {
      int row = tid >> 2, kg = tid & 3;
      const __bf16* gb = B + (long)(nbase + row) * K + k0 + kg * 8;
      char* lb = (char*)Bs + (wv * 64) * 16;
      async_copy16(gb, lb);
    }
    __syncthreads();
    bf16x8 af[4], bfr[2];
#pragma unroll
    for (int i = 0; i < 4; ++i)
      af[i] = *(const bf16x8*)&As[(wm * 64 + i * 16 + l15) * 32 + quad * 8];
#pragma unroll
    for (int j = 0; j < 2; ++j)
      bfr[j] = *(const bf16x8*)&Bs[(wn * 32 + j * 16 + l15) * 32 + quad * 8];
#pragma unroll
    for (int i = 0; i < 4; ++i)
#pragma unroll
      for (int j = 0; j < 2; ++j)
        acc[i][j] = __builtin_amdgcn_mfma_f32_16x16x32_bf16(bfr[j], af[i], acc[i][j], 0, 0, 0);
  }
  // swapped epilogue: row = ...+l15, cols = ...+quad*4+{0..3} -> float4 stores
#pragma unroll
  for (int i = 0; i < 4; ++i) {
    int row = mbase + wm * 64 + i * 16 + l15;
#pragma unroll
    for (int j = 0; j < 2; ++j) {
      int cb = nbase + wn * 32 + j * 16 + quad * 4;
      *(f32x4*)(C + (long)row * N + cb) = acc[i][j];
    }
  }
}

// ---------------- Flash attention (32 q-rows/wave, kt-split x4, XCD-local) ----------------
// Fixed-max softmax => l/o are plain sums over kt => kt-range splittable.
// Grid 512 x 512 thr (8 waves = 2 pairs x 4 quarters). Block b: h = (b&7)+8*((b>>3)&1),
// rest = b>>4 (0..31). Wave w: pr = w>>2, qtr = w&3. P = rest*2+pr (0..63).
// Passes: T = P then 127-P (32 q-rows); nkt = (T>>1)+1; quarter does [nkt*qtr/4, nkt*(qtr+1)/4).
// 512 blocks = 2 blocks/CU = 4 waves/SIMD. launch_bounds(512,2): do NOT tighten — (512,4)
// spilled o_acc/kc/va to scratch (R9: 1.3 GB HBM spill traffic, 5x regression).
__global__ __launch_bounds__(512, 2) void flash_attn(const __bf16* __restrict__ Qb,
                                                     const __bf16* __restrict__ Kf,
                                                     const __bf16* __restrict__ Vf,
                                                     __bf16* __restrict__ AO) {
  __shared__ float Ms[2][3][64][34];            // [pair][writer qtr-1][lane][32 o + 2 l]
  const int tid = threadIdx.x;
  const int lane = tid & 63, l15 = lane & 15, quad = lane >> 4;
  const int w = tid >> 6;                       // 0..7
  const int pr = w >> 2, qtr = w & 3;
  const int b = blockIdx.x;
  const int h = (b & 7) + 8 * ((b >> 3) & 1);
  const int rest = b >> 4;                      // 0..31
  const int P = rest * 2 + pr;                  // 0..63
  const int hoff = h * 64;

  const __bf16* Kh = Kf + (long)h * 64 * 4096;  // 64 tiles x 4096 elems
  const __bf16* Vh = Vf + (long)h * 64 * 4096;

  for (int pass = 0; pass < 2; ++pass) {
    const int T = pass ? (127 - P) : P;         // 32-row super-tile 0..127
    bf16x8 qf[2][2];
#pragma unroll
    for (int g = 0; g < 2; ++g) {
      const int qrow = T * 32 + g * 16 + l15;
      qf[g][0] = *(const bf16x8*)(Qb + (long)qrow * 1024 + hoff + quad * 8);
      qf[g][1] = *(const bf16x8*)(Qb + (long)qrow * 1024 + hoff + 32 + quad * 8);
    }

    const int nkt = (T >> 1) + 1;
    const int kt0 = (nkt * qtr) >> 2;
    const int kt1 = (nkt * (qtr + 1)) >> 2;
    f32x4 o_acc[2][4] = {};
    float l_acc[2] = {0.0f, 0.0f};

    // prefetch K frags for first kt (coalesced: lane*16B contiguous)
    bf16x8 kc[8];
    if (kt0 < kt1) {
      const __bf16* Kt = Kh + (long)kt0 * 4096;
#pragma unroll
      for (int f = 0; f < 8; ++f)
        kc[f] = *(const bf16x8*)(Kt + f * 512 + lane * 8);
    }

    for (int kt = kt0; kt < kt1; ++kt) {
      const __bf16* Vt = Vh + (long)kt * 4096;

      // V frags for this kt (issued early; used at the end of the iter)
      bf16x8 va[8];
#pragma unroll
      for (int f = 0; f < 8; ++f)
        va[f] = *(const bf16x8*)(Vt + f * 512 + lane * 8);

      // S^T: st[g][j][r] = S[q = T*32+g*16+l15][kt*64 + j*16 + quad*4 + r]
      f32x4 st[2][4] = {};
#pragma unroll
      for (int g = 0; g < 2; ++g)
#pragma unroll
        for (int j = 0; j < 4; ++j) {
          st[g][j] = __builtin_amdgcn_mfma_f32_16x16x32_bf16(kc[j * 2 + 0], qf[g][0], st[g][j], 0, 0, 0);
          st[g][j] = __builtin_amdgcn_mfma_f32_16x16x32_bf16(kc[j * 2 + 1], qf[g][1], st[g][j], 0, 0, 0);
        }

      // prefetch next K tile while softmax+PV run
      if (kt + 1 < kt1) {
        const __bf16* Kt = Kh + (long)(kt + 1) * 4096;
#pragma unroll
        for (int f = 0; f < 8; ++f)
          kc[f] = *(const bf16x8*)(Kt + f * 512 + lane * 8);
      }

      // causal mask (only the global last tile is partial; always in quarter 3)
      if (kt == nkt - 1) {
#pragma unroll
        for (int g = 0; g < 2; ++g) {
          const int dq = (T & 1) * 32 + g * 16 + l15;   // qrow - kt*64
#pragma unroll
          for (int j = 0; j < 4; ++j)
#pragma unroll
            for (int r = 0; r < 4; ++r)
              if (j * 16 + quad * 4 + r > dq) st[g][j][r] = -3.0e38f;
        }
      }

      // fixed-max softmax: p = 2^s (exact by shift-invariance; |s| bounded)
      bf16x4 pb[2][4];
#pragma unroll
      for (int g = 0; g < 2; ++g) {
        float ps = 0.0f;
#pragma unroll
        for (int j = 0; j < 4; ++j) {
          f32x4 pj;
#pragma unroll
          for (int r = 0; r < 4; ++r) pj[r] = __builtin_amdgcn_exp2f(st[g][j][r]);
          ps += (pj[0] + pj[1]) + (pj[2] + pj[3]);
          bf16x4 bb;
#pragma unroll
          for (int r = 0; r < 4; ++r) bb[r] = (__bf16)pj[r];
          pb[g][j] = bb;
        }
        l_acc[g] += ps;
      }

      // O^T += V^T * P^T : P^T already in K16 B-frag layout (registers)
#pragma unroll
      for (int g = 0; g < 2; ++g)
#pragma unroll
        for (int j = 0; j < 4; ++j) {
          bf16x4 pbj = pb[g][j];
#pragma unroll
          for (int jd = 0; jd < 4; ++jd) {
            bf16x8 v8 = va[jd * 2 + (j >> 1)];
            bf16x4 a4 = (j & 1) ? __builtin_shufflevector(v8, v8, 4, 5, 6, 7)
                                : __builtin_shufflevector(v8, v8, 0, 1, 2, 3);
            o_acc[g][jd] = mfma_k16(a4, pbj, o_acc[g][jd]);
          }
        }
    }

    // ---- merge 4 quarters via LDS (fixed-max => plain sums) ----
    if (qtr) {
#pragma unroll
      for (int g = 0; g < 2; ++g) {
#pragma unroll
        for (int jd = 0; jd < 4; ++jd)
#pragma unroll
          for (int r = 0; r < 4; ++r)
            Ms[pr][qtr - 1][lane][g * 16 + jd * 4 + r] = o_acc[g][jd][r];
        Ms[pr][qtr - 1][lane][32 + g] = l_acc[g];
      }
    }
    __syncthreads();
    if (!qtr) {
#pragma unroll
      for (int g = 0; g < 2; ++g) {
#pragma unroll
        for (int s = 0; s < 3; ++s)
#pragma unroll
          for (int jd = 0; jd < 4; ++jd)
#pragma unroll
            for (int r = 0; r < 4; ++r)
              o_acc[g][jd][r] += Ms[pr][s][lane][g * 16 + jd * 4 + r];
        float la = l_acc[g] + Ms[pr][0][lane][32 + g] + Ms[pr][1][lane][32 + g] + Ms[pr][2][lane][32 + g];
        la += __shfl_xor(la, 16);
        la += __shfl_xor(la, 32);
        const float inv = 1.0f / la;
        const int qrow = T * 32 + g * 16 + l15;
#pragma unroll
        for (int jd = 0; jd < 4; ++jd) {
          bf16x4 ob;
#pragma unroll
          for (int r = 0; r < 4; ++r) ob[r] = (__bf16)(o_acc[g][jd][r] * inv);
          *(bf16x4*)(AO + (long)qrow * 1024 + hoff + jd * 16 + quad * 4) = ob;
        }
      }
    }
    __syncthreads();  // Ms reused next pass
  }
}

// ---------------- launch ----------------
extern "C" void kernel_launch(void* const* d_in, const int* in_sizes, int n_in,
                              void* d_out, int out_size, void* d_ws, size_t ws_size,
                              hipStream_t stream) {
  const float* x  = (const float*)d_in[0];
  // d_in[1] = causal mask (structure known -> unused)
  const float* Wq = (const float*)d_in[2];
  const float* Wk = (const float*)d_in[3];
  const float* Wv = (const float*)d_in[4];
  const float* Wo = (const float*)d_in[5];
  float* out = (float*)d_out;

  char* ws = (char*)d_ws;
  __bf16* xb  = (__bf16*)ws;                    // 8 MB  [4096,1024]
  __bf16* Wc  = (__bf16*)(ws + (8u << 20));     // 6 MB  [3072,1024] = [Wq;Wk;Wv]
  __bf16* Wob = (__bf16*)(ws + (14u << 20));    // 2 MB  [1024,1024]
  __bf16* Qb  = (__bf16*)(ws + (16u << 20));    // 8 MB  [4096,1024]
  __bf16* Kfr = (__bf16*)(ws + (24u << 20));    // 8 MB  fragmented K
  __bf16* Vfr = (__bf16*)(ws + (32u << 20));    // 8 MB  fragmented V^T
  __bf16* AO  = (__bf16*)(ws + (40u << 20));    // 8 MB  [4096,1024]

  cvt_all<<<8192, 256, 0, stream>>>(x, Wq, Wk, Wv, Wo, xb, Wc, Wob);

  dim3 g1(3072 / 128, 4096 / 128);
  gemm_qkv<<<g1, 256, 0, stream>>>(xb, Wc, Qb, Kfr, Vfr);

  flash_attn<<<512, 512, 0, stream>>>(Qb, Kfr, Vfr, AO);

  dim3 g2(1024 / 64, 4096 / 128);
  gemm_wo<<<g2, 256, 0, stream>>>(AO, Wob, out);
}

// Round 11
// 232.796 us; speedup vs baseline: 2.0304x; 1.0364x over previous
//
#include <hip/hip_runtime.h>
#include <hip/hip_bf16.h>

// MHA forward: B=1, S=4096, D=1024, H=16, HD=64, causal, fp32 I/O, bf16 MFMA compute.
// cvt(all) -> QKV gemm (XCD-striped, swap-epilogue Q/K, pre-fragmented K/V)
//          -> flash (R8 config: 32 q-rows/wave, kt-split x2, fixed-max exp2, XCD-local)
//          -> Wo gemm (XCD-striped, swap-epilogue, float4 stores).

typedef __bf16 bf16x8 __attribute__((ext_vector_type(8)));
typedef __bf16 bf16x4 __attribute__((ext_vector_type(4)));
typedef float f32x4 __attribute__((ext_vector_type(4)));
typedef short s16x4 __attribute__((ext_vector_type(4)));

#define GAS __attribute__((address_space(1)))
#define LAS __attribute__((address_space(3)))

__device__ __forceinline__ void async_copy16(const void* g, void* l) {
  __builtin_amdgcn_global_load_lds((const GAS unsigned int*)g,
                                   (LAS unsigned int*)l, 16, 0, 0);
}

__device__ __forceinline__ f32x4 mfma_k16(bf16x4 a, bf16x4 b, f32x4 c) {
  union { bf16x4 h; s16x4 s; } ua, ub;
  ua.h = a; ub.h = b;
  return __builtin_amdgcn_mfma_f32_16x16x16bf16_1k(ua.s, ub.s, c, 0, 0, 0);
}

// ---------------- fused fp32 -> bf16 convert (x, Wq|Wk|Wv, Wo) ----------------
__global__ __launch_bounds__(256) void cvt_all(const float* __restrict__ x,
                                               const float* __restrict__ Wq,
                                               const float* __restrict__ Wk,
                                               const float* __restrict__ Wv,
                                               const float* __restrict__ Wo,
                                               __bf16* __restrict__ xb,
                                               __bf16* __restrict__ Wc,
                                               __bf16* __restrict__ Wob) {
  int b = blockIdx.x;
  const float* src;
  __bf16* dst;
  if (b < 4096)      { src = x  + (b       ) * 1024; dst = xb  + (long)b * 1024; }
  else if (b < 5120) { src = Wq + (b - 4096) * 1024; dst = Wc  + (long)(b - 4096) * 1024; }
  else if (b < 6144) { src = Wk + (b - 5120) * 1024; dst = Wc  + (1l << 20) + (long)(b - 5120) * 1024; }
  else if (b < 7168) { src = Wv + (b - 6144) * 1024; dst = Wc  + (2l << 20) + (long)(b - 6144) * 1024; }
  else               { src = Wo + (b - 7168) * 1024; dst = Wob + (long)(b - 7168) * 1024; }
  int i = threadIdx.x * 4;
  float4 f = *(const float4*)(src + i);
  bf16x4 o;
  o[0] = (__bf16)f.x; o[1] = (__bf16)f.y; o[2] = (__bf16)f.z; o[3] = (__bf16)f.w;
  *(bf16x4*)(dst + i) = o;
}

// ---------------- QKV GEMM: [4096,3072] = x[4096,1024] @ Wc[3072,1024]^T ----------------
// 1D grid of 768, XCD-striped: xcd = b&7 owns N-cols [xcd*3, xcd*3+3) (768 KB of Wc ->
// L2-resident); within XCD, n = q%3 inner so A-tile re-reads are consecutive (L2-hot).
// Q,K blocks use swapped MFMA (threads hold 4 consecutive out-cols -> vector stores).
// Frag layouts (per (h, 64-kt tile), 8 frags x 512 elems, flash loads frag_base + lane*8):
//   Kf frag(j,kk), lane(quad,l15): K[kt = j*16+l15][d = kk*32+quad*8+e], e=0..7
//   Vf frag(jd,jp), lane(quad,l15): V^T[d = jd*16+l15][kt = jp*32+(e>>2)*16+quad*4+(e&3)]
__global__ __launch_bounds__(256) void gemm_qkv(const __bf16* __restrict__ A,
                                                const __bf16* __restrict__ B,
                                                __bf16* __restrict__ Qb,
                                                __bf16* __restrict__ Kf,
                                                __bf16* __restrict__ Vf) {
  const int K = 1024;
  __shared__ __bf16 As[128 * 32];
  __shared__ __bf16 Bs[128 * 32];
  const int tid = threadIdx.x;
  const int lane = tid & 63, wv = tid >> 6;
  const int l15 = lane & 15, quad = lane >> 4;
  const int wm = wv >> 1, wn = wv & 1;
  const int bb = blockIdx.x;
  const int xcd = bb & 7, q = bb >> 3;          // q = 0..95
  const int nb = xcd * 3 + (q % 3);             // 0..23
  const int mb = q / 3;                         // 0..31
  const int mbase = mb * 128, nbase = nb * 128;
  const bool swp = (nbase < 2048);  // block-uniform: Q and K swapped, V not

  f32x4 acc[4][4] = {};

  for (int k0 = 0; k0 < K; k0 += 32) {
    __syncthreads();
#pragma unroll
    for (int p = 0; p < 2; ++p) {
      int i = p * 256 + tid;
      int row = i >> 2, kg = i & 3;
      const __bf16* ga = A + (long)(mbase + row) * K + k0 + kg * 8;
      const __bf16* gb = B + (long)(nbase + row) * K + k0 + kg * 8;
      char* la = (char*)As + (p * 256 + wv * 64) * 16;
      char* lb = (char*)Bs + (p * 256 + wv * 64) * 16;
      async_copy16(ga, la);
      async_copy16(gb, lb);
    }
    __syncthreads();
    bf16x8 af[4], bfr[4];
#pragma unroll
    for (int i = 0; i < 4; ++i)
      af[i] = *(const bf16x8*)&As[(wm * 64 + i * 16 + l15) * 32 + quad * 8];
#pragma unroll
    for (int j = 0; j < 4; ++j)
      bfr[j] = *(const bf16x8*)&Bs[(wn * 64 + j * 16 + l15) * 32 + quad * 8];
    if (swp) {
#pragma unroll
      for (int i = 0; i < 4; ++i)
#pragma unroll
        for (int j = 0; j < 4; ++j)
          acc[i][j] = __builtin_amdgcn_mfma_f32_16x16x32_bf16(bfr[j], af[i], acc[i][j], 0, 0, 0);
    } else {
#pragma unroll
      for (int i = 0; i < 4; ++i)
#pragma unroll
        for (int j = 0; j < 4; ++j)
          acc[i][j] = __builtin_amdgcn_mfma_f32_16x16x32_bf16(af[i], bfr[j], acc[i][j], 0, 0, 0);
    }
  }

  if (nbase < 1024) {
    // Q (swapped): thread holds row = mbase+wm*64+i*16+l15, cols cb..cb+3
    const float QS = 0.18033688011112043f;  // 0.125 * log2(e)
#pragma unroll
    for (int i = 0; i < 4; ++i) {
      int row = mbase + wm * 64 + i * 16 + l15;
#pragma unroll
      for (int j = 0; j < 4; ++j) {
        int cb = nbase + wn * 64 + j * 16 + quad * 4;
        union { __bf16 b[4]; uint2 u; } pk;
#pragma unroll
        for (int r = 0; r < 4; ++r) pk.b[r] = (__bf16)(acc[i][j][r] * QS);
        *(uint2*)(Qb + (long)row * 1024 + cb) = pk.u;
      }
    }
  } else if (nbase < 2048) {
    // K (swapped): acc[i][j][r] = K^T[d = nbase-1024+wn*64+j*16+quad*4+r][kt = mbase+wm*64+i*16+l15]
#pragma unroll
    for (int i = 0; i < 4; ++i)
#pragma unroll
      for (int j = 0; j < 4; ++j) {
        int d0 = nbase - 1024 + wn * 64 + j * 16 + quad * 4;  // 4 consecutive d
        int h = d0 >> 6, dd = d0 & 63;
        int kk = dd >> 5, qf = (dd >> 3) & 3, e0 = dd & 7;    // e0 in {0,4}
        int kt = mbase + wm * 64 + i * 16 + l15;
        int tile = kt >> 6;
        long off = ((long)(h * 64 + tile) * 8 + i * 2 + kk) * 512 + (qf * 16 + l15) * 8 + e0;
        union { __bf16 b[4]; uint2 u; } pk;
#pragma unroll
        for (int r = 0; r < 4; ++r) pk.b[r] = (__bf16)acc[i][j][r];
        *(uint2*)(Kf + off) = pk.u;
      }
  } else {
    // V (non-swapped): acc[i][j][r] = V[kt = mbase+wm*64+i*16+quad*4+r][d = nbase-2048+wn*64+j*16+l15]
#pragma unroll
    for (int i = 0; i < 4; ++i)
#pragma unroll
      for (int j = 0; j < 4; ++j) {
        int col = nbase - 2048 + wn * 64 + j * 16 + l15;
        int h = col >> 6, dd = col & 63;
        int jd = dd >> 4, lv = dd & 15;
        int kt0 = mbase + wm * 64 + i * 16 + quad * 4;   // 4 consecutive kt
        int tile = kt0 >> 6, w6 = kt0 & 63;
        int jp = w6 >> 5, bit4 = (w6 >> 4) & 1, qv = (w6 >> 2) & 3;
        long off = ((long)(h * 64 + tile) * 8 + jd * 2 + jp) * 512 + (qv * 16 + lv) * 8 + bit4 * 4;
        union { __bf16 b[4]; uint2 u; } pk;
#pragma unroll
        for (int r = 0; r < 4; ++r) pk.b[r] = (__bf16)acc[i][j][r];
        *(uint2*)(Vf + off) = pk.u;
      }
  }
}

// ---------------- Wo GEMM: out[4096,1024] = AO[4096,1024] @ Wo[1024,1024]^T (fp32 out) ----------------
// 1D grid of 512, XCD-striped (2 N-cols of 64 per XCD -> 256 KB Wob slice L2-resident).
// 128x64 tiles, swapped MFMA -> float4 epilogue stores.
__global__ __launch_bounds__(256) void gemm_wo(const __bf16* __restrict__ A,
                                               const __bf16* __restrict__ B,
                                               float* __restrict__ C) {
  const int K = 1024, N = 1024;
  __shared__ __bf16 As[128 * 32];
  __shared__ __bf16 Bs[64 * 32];
  const int tid = threadIdx.x;
  const int lane = tid & 63, wv = tid >> 6;
  const int l15 = lane & 15, quad = lane >> 4;
  const int wm = wv >> 1, wn = wv & 1;
  const int bb = blockIdx.x;
  const int xcd = bb & 7, q = bb >> 3;          // q = 0..63
  const int nb = xcd * 2 + (q & 1);             // 0..15
  const int mb = q >> 1;                        // 0..31
  const int mbase = mb * 128, nbase = nb * 64;

  f32x4 acc[4][2] = {};

  for (int k0 = 0; k0 < K; k0 += 32) {
    __syncthreads();
#pragma unroll
    for (int p = 0; p < 2; ++p) {
      int i = p * 256 + tid;
      int row = i >> 2, kg = i & 3;
      const __bf16* ga = A + (long)(mbase + row) * K + k0 + kg * 8;
      char* la = (char*)As + (p * 256 + wv * 64) * 16;
      async_copy16(ga, la);
    }
    {
      int row = tid >> 2, kg = tid & 3;
      const __bf16* gb = B + (long)(nbase + row) * K + k0 + kg * 8;
      char* lb = (char*)Bs + (wv * 64) * 16;
      async_copy16(gb, lb);
    }
    __syncthreads();
    bf16x8 af[4], bfr[2];
#pragma unroll
    for (int i = 0; i < 4; ++i)
      af[i] = *(const bf16x8*)&As[(wm * 64 + i * 16 + l15) * 32 + quad * 8];
#pragma unroll
    for (int j = 0; j < 2; ++j)
      bfr[j] = *(const bf16x8*)&Bs[(wn * 32 + j * 16 + l15) * 32 + quad * 8];
#pragma unroll
    for (int i = 0; i < 4; ++i)
#pragma unroll
      for (int j = 0; j < 2; ++j)
        acc[i][j] = __builtin_amdgcn_mfma_f32_16x16x32_bf16(bfr[j], af[i], acc[i][j], 0, 0, 0);
  }
  // swapped epilogue: row = ...+l15, cols = ...+quad*4+{0..3} -> float4 stores
#pragma unroll
  for (int i = 0; i < 4; ++i) {
    int row = mbase + wm * 64 + i * 16 + l15;
#pragma unroll
    for (int j = 0; j < 2; ++j) {
      int cb = nbase + wn * 32 + j * 16 + quad * 4;
      *(f32x4*)(C + (long)row * N + cb) = acc[i][j];
    }
  }
}

// ---------------- Flash attention (R8 config: 32 q-rows/wave, kt-split x2, XCD-local) ----------------
// Fixed-max softmax => l/o are plain sums over kt => kt-range splittable.
// Grid 256 x 512 thr (8 waves = 4 pairs x 2 halves). Block b: h = (b&7)+8*((b>>3)&1),
// rest = b>>4 (0..15). Wave w: pr = w>>1 (0..3), half = w&1. P = rest*4+pr (0..63).
// Passes: T = P then 127-P (32 q-rows); nkt = (T>>1)+1; half does [0,nkt/2) or [nkt/2,nkt).
// launch_bounds(512,2): do NOT tighten — (512,4) spilled o_acc/kc/va (R9: 1.3 GB spill).
// kt-split x4 also regressed (R10: 63 vs 54.8 µs — short loops can't amortize prefetch/merge).
__global__ __launch_bounds__(512, 2) void flash_attn(const __bf16* __restrict__ Qb,
                                                     const __bf16* __restrict__ Kf,
                                                     const __bf16* __restrict__ Vf,
                                                     __bf16* __restrict__ AO) {
  __shared__ float Ms[4][64][35];               // [pair][lane][32 o + 2 l + pad]
  const int tid = threadIdx.x;
  const int lane = tid & 63, l15 = lane & 15, quad = lane >> 4;
  const int w = tid >> 6;                       // 0..7
  const int pr = w >> 1, half = w & 1;
  const int b = blockIdx.x;
  const int h = (b & 7) + 8 * ((b >> 3) & 1);
  const int rest = b >> 4;                      // 0..15
  const int P = rest * 4 + pr;                  // 0..63
  const int hoff = h * 64;

  const __bf16* Kh = Kf + (long)h * 64 * 4096;  // 64 tiles x 4096 elems
  const __bf16* Vh = Vf + (long)h * 64 * 4096;

  for (int pass = 0; pass < 2; ++pass) {
    const int T = pass ? (127 - P) : P;         // 32-row super-tile 0..127
    bf16x8 qf[2][2];
#pragma unroll
    for (int g = 0; g < 2; ++g) {
      const int qrow = T * 32 + g * 16 + l15;
      qf[g][0] = *(const bf16x8*)(Qb + (long)qrow * 1024 + hoff + quad * 8);
      qf[g][1] = *(const bf16x8*)(Qb + (long)qrow * 1024 + hoff + 32 + quad * 8);
    }

    const int nkt = (T >> 1) + 1;
    const int kt0 = half ? (nkt >> 1) : 0;
    const int kt1 = half ? nkt : (nkt >> 1);
    f32x4 o_acc[2][4] = {};
    float l_acc[2] = {0.0f, 0.0f};

    // prefetch K frags for first kt (coalesced: lane*16B contiguous)
    bf16x8 kc[8];
    if (kt0 < kt1) {
      const __bf16* Kt = Kh + (long)kt0 * 4096;
#pragma unroll
      for (int f = 0; f < 8; ++f)
        kc[f] = *(const bf16x8*)(Kt + f * 512 + lane * 8);
    }

    for (int kt = kt0; kt < kt1; ++kt) {
      const __bf16* Vt = Vh + (long)kt * 4096;

      // V frags for this kt (issued early; used at the end of the iter)
      bf16x8 va[8];
#pragma unroll
      for (int f = 0; f < 8; ++f)
        va[f] = *(const bf16x8*)(Vt + f * 512 + lane * 8);

      // S^T: st[g][j][r] = S[q = T*32+g*16+l15][kt*64 + j*16 + quad*4 + r]
      f32x4 st[2][4] = {};
#pragma unroll
      for (int g = 0; g < 2; ++g)
#pragma unroll
        for (int j = 0; j < 4; ++j) {
          st[g][j] = __builtin_amdgcn_mfma_f32_16x16x32_bf16(kc[j * 2 + 0], qf[g][0], st[g][j], 0, 0, 0);
          st[g][j] = __builtin_amdgcn_mfma_f32_16x16x32_bf16(kc[j * 2 + 1], qf[g][1], st[g][j], 0, 0, 0);
        }

      // prefetch next K tile while softmax+PV run
      if (kt + 1 < kt1) {
        const __bf16* Kt = Kh + (long)(kt + 1) * 4096;
#pragma unroll
        for (int f = 0; f < 8; ++f)
          kc[f] = *(const bf16x8*)(Kt + f * 512 + lane * 8);
      }

      // causal mask (only the global last tile is partial; it lives in half==1)
      if (kt == nkt - 1) {
#pragma unroll
        for (int g = 0; g < 2; ++g) {
          const int dq = (T & 1) * 32 + g * 16 + l15;   // qrow - kt*64
#pragma unroll
          for (int j = 0; j < 4; ++j)
#pragma unroll
            for (int r = 0; r < 4; ++r)
              if (j * 16 + quad * 4 + r > dq) st[g][j][r] = -3.0e38f;
        }
      }

      // fixed-max softmax: p = 2^s (exact by shift-invariance; |s| bounded)
      bf16x4 pb[2][4];
#pragma unroll
      for (int g = 0; g < 2; ++g) {
        float ps = 0.0f;
#pragma unroll
        for (int j = 0; j < 4; ++j) {
          f32x4 pj;
#pragma unroll
          for (int r = 0; r < 4; ++r) pj[r] = __builtin_amdgcn_exp2f(st[g][j][r]);
          ps += (pj[0] + pj[1]) + (pj[2] + pj[3]);
          bf16x4 bb16;
#pragma unroll
          for (int r = 0; r < 4; ++r) bb16[r] = (__bf16)pj[r];
          pb[g][j] = bb16;
        }
        l_acc[g] += ps;
      }

      // O^T += V^T * P^T : P^T already in K16 B-frag layout (registers)
#pragma unroll
      for (int g = 0; g < 2; ++g)
#pragma unroll
        for (int j = 0; j < 4; ++j) {
          bf16x4 pbj = pb[g][j];
#pragma unroll
          for (int jd = 0; jd < 4; ++jd) {
            bf16x8 v8 = va[jd * 2 + (j >> 1)];
            bf16x4 a4 = (j & 1) ? __builtin_shufflevector(v8, v8, 4, 5, 6, 7)
                                : __builtin_shufflevector(v8, v8, 0, 1, 2, 3);
            o_acc[g][jd] = mfma_k16(a4, pbj, o_acc[g][jd]);
          }
        }
    }

    // ---- merge halves via LDS (fixed-max => plain sums) ----
    if (half) {
#pragma unroll
      for (int g = 0; g < 2; ++g) {
#pragma unroll
        for (int jd = 0; jd < 4; ++jd)
#pragma unroll
          for (int r = 0; r < 4; ++r)
            Ms[pr][lane][g * 16 + jd * 4 + r] = o_acc[g][jd][r];
        Ms[pr][lane][32 + g] = l_acc[g];
      }
    }
    __syncthreads();
    if (!half) {
#pragma unroll
      for (int g = 0; g < 2; ++g) {
#pragma unroll
        for (int jd = 0; jd < 4; ++jd)
#pragma unroll
          for (int r = 0; r < 4; ++r)
            o_acc[g][jd][r] += Ms[pr][lane][g * 16 + jd * 4 + r];
        float la = l_acc[g] + Ms[pr][lane][32 + g];
        la += __shfl_xor(la, 16);
        la += __shfl_xor(la, 32);
        const float inv = 1.0f / la;
        const int qrow = T * 32 + g * 16 + l15;
#pragma unroll
        for (int jd = 0; jd < 4; ++jd) {
          bf16x4 ob;
#pragma unroll
          for (int r = 0; r < 4; ++r) ob[r] = (__bf16)(o_acc[g][jd][r] * inv);
          *(bf16x4*)(AO + (long)qrow * 1024 + hoff + jd * 16 + quad * 4) = ob;
        }
      }
    }
    __syncthreads();  // Ms reused next pass
  }
}

// ---------------- launch ----------------
extern "C" void kernel_launch(void* const* d_in, const int* in_sizes, int n_in,
                              void* d_out, int out_size, void* d_ws, size_t ws_size,
                              hipStream_t stream) {
  const float* x  = (const float*)d_in[0];
  // d_in[1] = causal mask (structure known -> unused)
  const float* Wq = (const float*)d_in[2];
  const float* Wk = (const float*)d_in[3];
  const float* Wv = (const float*)d_in[4];
  const float* Wo = (const float*)d_in[5];
  float* out = (float*)d_out;

  char* ws = (char*)d_ws;
  __bf16* xb  = (__bf16*)ws;                    // 8 MB  [4096,1024]
  __bf16* Wc  = (__bf16*)(ws + (8u << 20));     // 6 MB  [3072,1024] = [Wq;Wk;Wv]
  __bf16* Wob = (__bf16*)(ws + (14u << 20));    // 2 MB  [1024,1024]
  __bf16* Qb  = (__bf16*)(ws + (16u << 20));    // 8 MB  [4096,1024]
  __bf16* Kfr = (__bf16*)(ws + (24u << 20));    // 8 MB  fragmented K
  __bf16* Vfr = (__bf16*)(ws + (32u << 20));    // 8 MB  fragmented V^T
  __bf16* AO  = (__bf16*)(ws + (40u << 20));    // 8 MB  [4096,1024]

  cvt_all<<<8192, 256, 0, stream>>>(x, Wq, Wk, Wv, Wo, xb, Wc, Wob);

  gemm_qkv<<<768, 256, 0, stream>>>(xb, Wc, Qb, Kfr, Vfr);

  flash_attn<<<256, 512, 0, stream>>>(Qb, Kfr, Vfr, AO);

  gemm_wo<<<512, 256, 0, stream>>>(AO, Wob, out);
}